// Round 12
// baseline (60.178 us; speedup 1.0000x reference)
//
#include <hip/hip_runtime.h>

#define NTOK 16384
#define NC 2048
#define C4 512            // float4 per row
#define NE 8
#define TPB 256           // 4 waves
#define TOKW 2            // tokens per wave
#define TOK_PER_BLOCK 8   // 4 waves x 2 tokens
#define NBLK (NTOK / TOK_PER_BLOCK)   // 2048

// Lore (R1-R11):
//  - VGPR cap = 256/launch_bounds_arg2: (256,2)->128 OK; (.,4)->64 -> spill.
//  - ALL register-array indices must be compile-time (rule #20).
//  - R11 fail: full-unroll WITHOUT sched pinning hoists gate loads too ->
//    >128 live regs -> spill. R12: sched_barrier(0) per k-iter caps in-flight
//    gate loads at 8 while keeping all 16 x-loads in flight.
//  - LDS gate staging (R9) regressed; L1/L2 hits beat ds_read+barrier here.
//  - >=4096 waves required (R7/R10); gate-byte halving neutral (R6==R8).
__global__ __launch_bounds__(TPB, 2) void router_kernel(
    const float* __restrict__ x, const float* __restrict__ gw,
    float* __restrict__ out, float* __restrict__ ws) {
    __shared__ float s_psum[NE];
    __shared__ float s_cnt[NE];

    const int tid = threadIdx.x;
    if (tid < NE) { s_psum[tid] = 0.0f; s_cnt[tid] = 0.0f; }
    __syncthreads();

    const int wave = tid >> 6;
    const int lane = tid & 63;
    const float4* x4 = (const float4*)x;
    const float4* gw4 = (const float4*)gw;
    const int t0 = blockIdx.x * TOK_PER_BLOCK + wave * TOKW;

    float* out_w = out;               // weights [N,2]
    float* out_i = out + 2 * NTOK;    // indices [N,2] stored as float

    // ---- deep prefetch: ALL 16 x-loads issued before any compute ----
    float4 xv0[8], xv1[8];
    const float4* xr0 = x4 + (size_t)(t0 + 0) * C4 + lane;
    const float4* xr1 = x4 + (size_t)(t0 + 1) * C4 + lane;
    #pragma unroll
    for (int k = 0; k < 8; ++k) {
        xv0[k] = xr0[k * 64];
        xv1[k] = xr1[k * 64];
    }
    // pin: nothing from the compute loop may move above this point
    __builtin_amdgcn_sched_barrier(0);

    float acc0[NE], acc1[NE];
    #pragma unroll
    for (int e = 0; e < NE; ++e) { acc0[e] = 0.0f; acc1[e] = 0.0f; }

    #pragma unroll
    for (int k = 0; k < 8; ++k) {
        const int idx = lane + k * 64;
        #pragma unroll
        for (int e = 0; e < NE; ++e) {
            const float4 wv = gw4[e * C4 + idx];   // short-latency L1/L2 hit
            acc0[e] += xv0[k].x * wv.x + xv0[k].y * wv.y +
                       xv0[k].z * wv.z + xv0[k].w * wv.w;
            acc1[e] += xv1[k].x * wv.x + xv1[k].y * wv.y +
                       xv1[k].z * wv.z + xv1[k].w * wv.w;
        }
        // forbid hoisting next iteration's gate loads above this point:
        // caps in-flight gate loads at 8 -> no spill (R11 lesson)
        __builtin_amdgcn_sched_barrier(0);
    }

    // butterfly reduce over 64 lanes: every lane ends with full sums
    #pragma unroll
    for (int off = 32; off >= 1; off >>= 1) {
        #pragma unroll
        for (int e = 0; e < NE; ++e) {
            acc0[e] += __shfl_xor(acc0[e], off, 64);
            acc1[e] += __shfl_xor(acc1[e], off, 64);
        }
    }

    // lane processes token (lane&1) -- static select (rule #20)
    const int t = lane & 1;
    float l[NE];
    #pragma unroll
    for (int e = 0; e < NE; ++e) l[e] = t ? acc1[e] : acc0[e];

    float mx = l[0];
    #pragma unroll
    for (int e = 1; e < NE; ++e) mx = fmaxf(mx, l[e]);
    float p[NE];
    float s = 0.0f;
    #pragma unroll
    for (int e = 0; e < NE; ++e) { p[e] = expf(l[e] - mx); s += p[e]; }
    const float inv = 1.0f / s;
    #pragma unroll
    for (int e = 0; e < NE; ++e) p[e] *= inv;

    // top-2, ties -> lower index (matches jax.lax.top_k)
    int i0 = 0; float p0 = p[0];
    #pragma unroll
    for (int e = 1; e < NE; ++e) if (p[e] > p0) { p0 = p[e]; i0 = e; }
    int i1 = (i0 == 0) ? 1 : 0; float p1 = p[i1];
    #pragma unroll
    for (int e = 0; e < NE; ++e)
        if (e != i0 && p[e] > p1) { p1 = p[e]; i1 = e; }

    if (lane < TOKW) {
        const int token = t0 + lane;
        const float wsum = p0 + p1;
        out_w[2 * token]     = p0 / wsum;
        out_w[2 * token + 1] = p1 / wsum;
        out_i[2 * token]     = (float)i0;
        out_i[2 * token + 1] = (float)i1;

        #pragma unroll
        for (int e = 0; e < NE; ++e) atomicAdd(&s_psum[e], p[e]);
        atomicAdd(&s_cnt[i0], 1.0f);
        atomicAdd(&s_cnt[i1], 1.0f);
    }

    __syncthreads();
    // non-atomic per-block partials -> no zero-init kernel needed
    if (tid < NE)          ws[blockIdx.x * 16 + tid] = s_psum[tid];
    else if (tid < 2 * NE) ws[blockIdx.x * 16 + tid] = s_cnt[tid - NE];
}

__global__ void finalize_kernel(const float* __restrict__ ws,
                                float* __restrict__ out) {
    __shared__ float red[16];
    const int tid = threadIdx.x;   // 1024 threads
    if (tid < 16) red[tid] = 0.0f;
    __syncthreads();
    const int i = tid & 15;
    float sum = 0.0f;
    for (int b = (tid >> 4); b < NBLK; b += 64)
        sum += ws[b * 16 + i];
    atomicAdd(&red[i], sum);
    __syncthreads();
    if (tid == 0) {
        float aux = 0.0f;
        #pragma unroll
        for (int e = 0; e < NE; ++e)
            aux += (red[NE + e] * (1.0f / NTOK)) * (red[e] * (1.0f / NTOK));
        out[4 * NTOK] = (float)NE * aux;
    }
}

extern "C" void kernel_launch(void* const* d_in, const int* in_sizes, int n_in,
                              void* d_out, int out_size, void* d_ws, size_t ws_size,
                              hipStream_t stream) {
    const float* x  = (const float*)d_in[0];   // [4,4096,2048] f32
    const float* gw = (const float*)d_in[1];   // [8,2048] f32
    float* out = (float*)d_out;                // weights[N,2] | indices[N,2] | aux
    float* ws  = (float*)d_ws;                 // per-block partials [NBLK][16]

    router_kernel<<<NBLK, TPB, 0, stream>>>(x, gw, out, ws);
    finalize_kernel<<<1, 1024, 0, stream>>>(ws, out);
}

// Round 13
// 50.732 us; speedup vs baseline: 1.1862x; 1.1862x over previous
//
#include <hip/hip_runtime.h>

#define NTOK 16384
#define NC 2048
#define C4 512            // float4 per row
#define NE 8
#define TPB 256           // 4 waves
#define TOKB 8            // tokens per block
#define NBLK (NTOK / TOKB)   // 2048
#define CHUNK 64          // float4 per chunk per row (1 KB)
#define NCHUNK (C4 / CHUNK)  // 8

// Lore (R1-R12):
//  - Compiler serializes register loads via reg-reuse (R10/R12: VGPR=68 proves
//    <=2 x-loads in flight) -> latency-bound, ~43us floor for register MLP.
//  - Fix: MLP via global_load_lds queue (zero VGPR, deep), m97 pattern:
//    stage(k+1) -> compute(k) -> __syncthreads (drains vmcnt).
//  - VGPR cap = 256/launch_bounds_arg2; (256,2)->128 cap.
//  - All register-array indices compile-time (rule #20).
//  - LDS gate staging regressed (R9) -> gate stays on L1 path.

typedef const unsigned int __attribute__((address_space(1)))* gk_gptr_t;
typedef unsigned int __attribute__((address_space(3)))* gk_sptr_t;

__global__ __launch_bounds__(TPB, 2) void router_kernel(
    const float* __restrict__ x, const float* __restrict__ gw,
    float* __restrict__ out, float* __restrict__ ws) {
    __shared__ float4 tile[2][TOKB][CHUNK];   // 16 KB, double-buffered x chunks
    __shared__ float s_psum[NE];
    __shared__ float s_cnt[NE];

    const int tid = threadIdx.x;
    if (tid < NE) { s_psum[tid] = 0.0f; s_cnt[tid] = 0.0f; }

    const int wave = tid >> 6;
    const int lane = tid & 63;
    const float4* x4 = (const float4*)x;
    const float4* gw4 = (const float4*)gw;
    const int T0 = blockIdx.x * TOKB;
    const int rA = wave;          // rows (tokens) this wave stages AND computes
    const int rB = wave + 4;

    const float4* srcA = x4 + (size_t)(T0 + rA) * C4 + lane;
    const float4* srcB = x4 + (size_t)(T0 + rB) * C4 + lane;

    float* out_w = out;               // weights [N,2]
    float* out_i = out + 2 * NTOK;    // indices [N,2] stored as float

    // prologue: stage chunk 0 into buf 0 (wave-uniform LDS base + lane*16)
    __builtin_amdgcn_global_load_lds((gk_gptr_t)(const void*)srcA,
                                     (gk_sptr_t)(void*)&tile[0][rA][0], 16, 0, 0);
    __builtin_amdgcn_global_load_lds((gk_gptr_t)(const void*)srcB,
                                     (gk_sptr_t)(void*)&tile[0][rB][0], 16, 0, 0);

    float accA[NE], accB[NE];
    #pragma unroll
    for (int e = 0; e < NE; ++e) { accA[e] = 0.0f; accB[e] = 0.0f; }

    #pragma unroll 1
    for (int k = 0; k < NCHUNK; ++k) {
        const int cur = k & 1;
        __syncthreads();   // vmcnt(0): buf[cur] (chunk k) ready; prev reads done

        if (k + 1 < NCHUNK) {   // stage chunk k+1 into the other buffer
            __builtin_amdgcn_global_load_lds(
                (gk_gptr_t)(const void*)(srcA + (k + 1) * CHUNK),
                (gk_sptr_t)(void*)&tile[cur ^ 1][rA][0], 16, 0, 0);
            __builtin_amdgcn_global_load_lds(
                (gk_gptr_t)(const void*)(srcB + (k + 1) * CHUNK),
                (gk_sptr_t)(void*)&tile[cur ^ 1][rB][0], 16, 0, 0);
        }

        // compute chunk k: x from LDS (short latency), gate from L1
        const float4 xa = tile[cur][rA][lane];
        const float4 xb = tile[cur][rB][lane];
        const int idx = lane + k * CHUNK;
        #pragma unroll
        for (int e = 0; e < NE; ++e) {
            const float4 wv = gw4[e * C4 + idx];
            accA[e] += xa.x * wv.x + xa.y * wv.y + xa.z * wv.z + xa.w * wv.w;
            accB[e] += xb.x * wv.x + xb.y * wv.y + xb.z * wv.z + xb.w * wv.w;
        }
    }

    // butterfly reduce over 64 lanes: every lane ends with full sums
    #pragma unroll
    for (int off = 32; off >= 1; off >>= 1) {
        #pragma unroll
        for (int e = 0; e < NE; ++e) {
            accA[e] += __shfl_xor(accA[e], off, 64);
            accB[e] += __shfl_xor(accB[e], off, 64);
        }
    }

    // lane processes token rA (lane even) or rB (lane odd) -- static select
    const int t = lane & 1;
    float l[NE];
    #pragma unroll
    for (int e = 0; e < NE; ++e) l[e] = t ? accB[e] : accA[e];

    float mx = l[0];
    #pragma unroll
    for (int e = 1; e < NE; ++e) mx = fmaxf(mx, l[e]);
    float p[NE];
    float s = 0.0f;
    #pragma unroll
    for (int e = 0; e < NE; ++e) { p[e] = expf(l[e] - mx); s += p[e]; }
    const float inv = 1.0f / s;
    #pragma unroll
    for (int e = 0; e < NE; ++e) p[e] *= inv;

    // top-2, ties -> lower index (matches jax.lax.top_k)
    int i0 = 0; float p0 = p[0];
    #pragma unroll
    for (int e = 1; e < NE; ++e) if (p[e] > p0) { p0 = p[e]; i0 = e; }
    int i1 = (i0 == 0) ? 1 : 0; float p1 = p[i1];
    #pragma unroll
    for (int e = 0; e < NE; ++e)
        if (e != i0 && p[e] > p1) { p1 = p[e]; i1 = e; }

    if (lane < 2) {
        const int token = T0 + (t ? rB : rA);
        const float wsum = p0 + p1;
        out_w[2 * token]     = p0 / wsum;
        out_w[2 * token + 1] = p1 / wsum;
        out_i[2 * token]     = (float)i0;
        out_i[2 * token + 1] = (float)i1;

        #pragma unroll
        for (int e = 0; e < NE; ++e) atomicAdd(&s_psum[e], p[e]);
        atomicAdd(&s_cnt[i0], 1.0f);
        atomicAdd(&s_cnt[i1], 1.0f);
    }

    __syncthreads();
    // non-atomic per-block partials -> no zero-init kernel needed
    if (tid < NE)          ws[blockIdx.x * 16 + tid] = s_psum[tid];
    else if (tid < 2 * NE) ws[blockIdx.x * 16 + tid] = s_cnt[tid - NE];
}

__global__ void finalize_kernel(const float* __restrict__ ws,
                                float* __restrict__ out) {
    __shared__ float red[16];
    const int tid = threadIdx.x;   // 1024 threads
    if (tid < 16) red[tid] = 0.0f;
    __syncthreads();
    const int i = tid & 15;
    float sum = 0.0f;
    for (int b = (tid >> 4); b < NBLK; b += 64)
        sum += ws[b * 16 + i];
    atomicAdd(&red[i], sum);
    __syncthreads();
    if (tid == 0) {
        float aux = 0.0f;
        #pragma unroll
        for (int e = 0; e < NE; ++e)
            aux += (red[NE + e] * (1.0f / NTOK)) * (red[e] * (1.0f / NTOK));
        out[4 * NTOK] = (float)NE * aux;
    }
}

extern "C" void kernel_launch(void* const* d_in, const int* in_sizes, int n_in,
                              void* d_out, int out_size, void* d_ws, size_t ws_size,
                              hipStream_t stream) {
    const float* x  = (const float*)d_in[0];   // [4,4096,2048] f32
    const float* gw = (const float*)d_in[1];   // [8,2048] f32
    float* out = (float*)d_out;                // weights[N,2] | indices[N,2] | aux
    float* ws  = (float*)d_ws;                 // per-block partials [NBLK][16]

    router_kernel<<<NBLK, TPB, 0, stream>>>(x, gw, out, ws);
    finalize_kernel<<<1, 1024, 0, stream>>>(ws, out);
}